// Round 8
// baseline (152.168 us; speedup 1.0000x reference)
//
#include <hip/hip_runtime.h>
#include <hip/hip_bf16.h>
#include <math.h>

#define B_ 8
#define N_ 512
#define K_ 128
#define M_ 100
#define NPAIR (B_*N_)    // 4096
#define DRLEN 1600
#define F0 240
#define NPAD 256

#define NLUT 2048
#define LUT2_STRIDE 128      // float2 per row (100 used)
#define SMAX 1.5f
#define EPB 8                // LUT entries per block

using bf16x8 = __attribute__((ext_vector_type(8))) __bf16;
using f32x4  = __attribute__((ext_vector_type(4))) float;

static __device__ __forceinline__ float tanh_f(float x){
  float xc = fminf(fmaxf(x, -15.f), 15.f);
  float e = __expf(2.f*xc);
  return __fdividef(e - 1.f, e + 1.f);
}

// ---------------------------------------------------------------------------
// Fused prep: region A = W0 transpose (blocks 0..99), region B = W1T/W2T/bias
// (blocks 100..614), region C = LUT build (blocks 615..870).
// LUT stored PAIRED: T2[e][m] = (G_e[m], G_{e+1}[m]) so embed does one 8B
// load per (j,m) instead of two 4B loads 512B apart.
// ---------------------------------------------------------------------------
#define W0T_BLOCKS 100                                 // 25 x 4 tiles
#define SMALL_ELEMS (2*NPAD*NPAD + 3*NPAD)             // 131840
#define SMALL_BLOCKS ((SMALL_ELEMS + 255)/256)         // 515
#define LUT_BLOCKS (NLUT/EPB)                          // 256

__global__ __launch_bounds__(256) void prep_fused(
    const float* __restrict__ fw0, const float* __restrict__ fw1,
    const float* __restrict__ fw2,
    const float* __restrict__ fb0, const float* __restrict__ fb1,
    const float* __restrict__ fb2,
    const float* __restrict__ ew0, const float* __restrict__ eb0,
    const float* __restrict__ ew1, const float* __restrict__ eb1,
    const float* __restrict__ ew2, const float* __restrict__ eb2,
    __hip_bfloat16* __restrict__ W0T, __hip_bfloat16* __restrict__ W1T,
    __hip_bfloat16* __restrict__ W2T,
    float* __restrict__ b0p, float* __restrict__ b1p, float* __restrict__ b2p,
    float2* __restrict__ T2)
{
  __shared__ float tile[64][65];
  __shared__ float sh0[EPB][26];
  __shared__ float sh1[EPB][52];
  const int bb = blockIdx.x;
  const int t = threadIdx.x;

  if (bb < W0T_BLOCKS){
    // ---- W0 transpose: src [1600][240] f32 -> [256][1600] bf16 ----
    const int k0 = (bb % 25) * 64;
    const int n0 = (bb / 25) * 64;
    const int tc = t & 63, tr = t >> 6;
    #pragma unroll
    for (int i = 0; i < 16; i++){
      int r = i*4 + tr;
      int n = n0 + tc;
      tile[r][tc] = (n < F0) ? fw0[(size_t)(k0 + r)*F0 + n] : 0.f;
    }
    __syncthreads();
    #pragma unroll
    for (int i = 0; i < 16; i++){
      int r = i*4 + tr;
      W0T[(size_t)(n0 + r)*DRLEN + k0 + tc] = __float2bfloat16(tile[tc][r]);
    }
  } else if (bb < W0T_BLOCKS + SMALL_BLOCKS){
    // ---- W1T / W2T / biases ----
    int idx = (bb - W0T_BLOCKS)*256 + t;
    if (idx < NPAD*NPAD){
      int n = idx / NPAD, k = idx % NPAD;
      W1T[idx] = __float2bfloat16((n < F0 && k < F0) ? fw1[(size_t)k*F0 + n] : 0.f);
    } else if (idx < 2*NPAD*NPAD){
      int j = idx - NPAD*NPAD;
      int n = j / NPAD, k = j % NPAD;
      W2T[j] = __float2bfloat16((n < F0 && k < F0) ? fw2[(size_t)k*F0 + n] : 0.f);
    } else if (idx < SMALL_ELEMS){
      int j = idx - 2*NPAD*NPAD;
      int which = j / NPAD, c = j % NPAD;
      const float* s = (which == 0) ? fb0 : (which == 1) ? fb1 : fb2;
      float* d = (which == 0) ? b0p : (which == 1) ? b1p : b2p;
      d[c] = (c < F0) ? s[c] : 0.f;
    }
  } else {
    // ---- LUT build (paired layout) ----
    const int e0 = (bb - W0T_BLOCKS - SMALL_BLOCKS) * EPB;
    if (t < EPB*25){
      int e = t / 25, c = t % 25;
      float S = (float)(e0 + e) * (SMAX / (float)(NLUT - 1));
      sh0[e][c] = tanh_f(fmaf(S, ew0[c], eb0[c]));
    }
    __syncthreads();
    for (int o = t; o < EPB*50; o += 256){
      int e = o / 50, c = o % 50;
      float a = eb1[c], b = 0.f;
      #pragma unroll
      for (int k = 0; k < 24; k += 2){
        a = fmaf(sh0[e][k],   ew1[k*50 + c],     a);
        b = fmaf(sh0[e][k+1], ew1[(k+1)*50 + c], b);
      }
      a = fmaf(sh0[e][24], ew1[24*50 + c], a);
      sh1[e][c] = tanh_f(a + b);
    }
    __syncthreads();
    for (int o = t; o < EPB*M_; o += 256){
      int e = o / M_, c = o % M_;
      float a = eb2[c], b = 0.f;
      #pragma unroll
      for (int k = 0; k < 50; k += 2){
        a = fmaf(sh1[e][k],   ew2[k*M_ + c],     a);
        b = fmaf(sh1[e][k+1], ew2[(k+1)*M_ + c], b);
      }
      float g = tanh_f(a + b);
      int ge = e0 + e;
      T2[(size_t)ge*LUT2_STRIDE + c].x = g;          // pair head
      if (ge > 0)
        T2[(size_t)(ge-1)*LUT2_STRIDE + c].y = g;    // pair tail of prev
    }
  }
}

// ---------------------------------------------------------------------------
// Embed: per (b,n) pair; paired-LUT lerp; DR out in bf16 [pair][1600].
// ---------------------------------------------------------------------------
__global__ __launch_bounds__(128) void embed_kernel(
    const float* __restrict__ img, const float2* __restrict__ T2,
    __hip_bfloat16* __restrict__ DR)
{
  __shared__ float4 sRi[K_];     // 2 KB
  __shared__ int    sJ[K_];      // premultiplied row offset (i * LUT2_STRIDE)
  __shared__ float  sW[K_];      // lerp weight
  __shared__ float  sB[4][M_];

  const int pair = blockIdx.x;
  const int t = threadIdx.x;

  {
    float4 v = *(const float4*)(img + ((size_t)pair*K_ + t)*4);
    float x = v.x, y = v.y, z = v.z, fl = v.w;
    float R = fmaf(x, x, fmaf(y, y, z*z));
    bool mask = fl > 0.f;
    bool lt10 = R < 10.f;
    float safe = (R == 0.f) ? 1.f : R;
    float Sc = 0.5f*cosf(0.20943951023931953f*(R - 10.f)) + 0.5f;
    float S;
    if (mask && lt10)            S = 1.f/safe;
    else if (!lt10 && R < 25.f)  S = Sc;
    else                         S = 0.f;
    float coef = mask ? S/safe : 0.f;
    sRi[t] = make_float4(S, coef*x, coef*y, coef*z);

    float fidx = fminf(S, SMAX) * ((float)(NLUT - 1) / SMAX);
    float fi = floorf(fidx);
    int i = (int)fi;
    float w = fidx - fi;
    if (i > NLUT - 2){ i = NLUT - 2; w = 1.f; }
    sJ[t] = i * LUT2_STRIDE;
    sW[t] = w;
  }
  __syncthreads();

  if (t < M_){
    const int m = t;
    float a0 = 0.f, a1 = 0.f, a2 = 0.f, a3 = 0.f;
    #pragma unroll 4
    for (int j = 0; j < K_; j++){
      int off = sJ[j];
      float w = sW[j];
      float4 ri = sRi[j];
      float2 tv = T2[off + m];                 // one coalesced 8B load
      float g = fmaf(w, tv.y - tv.x, tv.x);
      a0 = fmaf(ri.x, g, a0);
      a1 = fmaf(ri.y, g, a1);
      a2 = fmaf(ri.z, g, a2);
      a3 = fmaf(ri.w, g, a3);
    }
    sB[0][m] = a0; sB[1][m] = a1; sB[2][m] = a2; sB[3][m] = a3;
  }
  __syncthreads();

  __hip_bfloat16* drp = DR + (size_t)pair*DRLEN;
  for (int o = t; o < DRLEN; o += 128){
    int m = o / M_, h = o % M_;
    float d = sB[0][m]*sB[0][h] + sB[1][m]*sB[1][h]
            + sB[2][m]*sB[2][h] + sB[3][m]*sB[3][h];
    drp[o] = __float2bfloat16(d);
  }
}

// ---------------------------------------------------------------------------
// LDS double-buffered MFMA GEMM, fully unrolled (compile-time indices).
// Y[M][256] = tanh(A @ Bt^T + bias). BM=BN=BK=64, 4 waves 2x2, tile 32x32.
// ---------------------------------------------------------------------------
template<int KK, int NITER>
__global__ __launch_bounds__(256) void gemm_lds(
    const __hip_bfloat16* __restrict__ A_, const __hip_bfloat16* __restrict__ Bt_,
    const float* __restrict__ bias, __hip_bfloat16* __restrict__ Y)
{
  __shared__ __align__(16) __bf16 As[2][64][72];
  __shared__ __align__(16) __bf16 Bs[2][64][72];

  const __bf16* A  = (const __bf16*)A_;
  const __bf16* Bt = (const __bf16*)Bt_;
  const int tid = threadIdx.x;
  const int lane = tid & 63, wave = tid >> 6;
  const int wm = wave & 1, wn = wave >> 1;
  const int l15 = lane & 15, q = lane >> 4;
  const int row0 = blockIdx.x * 64;
  const int col0 = blockIdx.y * 64;

  int arow[2], ac8[2]; size_t aoff[2], boff[2];
  #pragma unroll
  for (int i = 0; i < 2; i++){
    int cid = tid + i*256; arow[i] = cid >> 3; ac8[i] = cid & 7;
    aoff[i] = (size_t)(row0 + arow[i])*KK + ac8[i]*8;
    boff[i] = (size_t)(col0 + arow[i])*KK + ac8[i]*8;
  }

  bf16x8 Ar[2][2], Br[2][2];

  #pragma unroll
  for (int i = 0; i < 2; i++) Ar[0][i] = *(const bf16x8*)(A + aoff[i]);
  #pragma unroll
  for (int i = 0; i < 2; i++) Br[0][i] = *(const bf16x8*)(Bt + boff[i]);
  #pragma unroll
  for (int i = 0; i < 2; i++) *(bf16x8*)&As[0][arow[i]][ac8[i]*8] = Ar[0][i];
  #pragma unroll
  for (int i = 0; i < 2; i++) *(bf16x8*)&Bs[0][arow[i]][ac8[i]*8] = Br[0][i];
  #pragma unroll
  for (int i = 0; i < 2; i++) Ar[1][i] = *(const bf16x8*)(A + aoff[i] + 64);
  #pragma unroll
  for (int i = 0; i < 2; i++) Br[1][i] = *(const bf16x8*)(Bt + boff[i] + 64);
  __syncthreads();

  f32x4 acc[2][2] = {};

  #pragma unroll
  for (int it = 0; it < NITER; it++){
    const int buf = it & 1;
    #pragma unroll
    for (int ks = 0; ks < 2; ks++){
      bf16x8 a0 = *(const bf16x8*)&As[buf][wm*32 +      l15][ks*32 + q*8];
      bf16x8 a1 = *(const bf16x8*)&As[buf][wm*32 + 16 + l15][ks*32 + q*8];
      bf16x8 b0 = *(const bf16x8*)&Bs[buf][wn*32 +      l15][ks*32 + q*8];
      bf16x8 b1 = *(const bf16x8*)&Bs[buf][wn*32 + 16 + l15][ks*32 + q*8];
      acc[0][0] = __builtin_amdgcn_mfma_f32_16x16x32_bf16(a0, b0, acc[0][0], 0,0,0);
      acc[1][0] = __builtin_amdgcn_mfma_f32_16x16x32_bf16(a1, b0, acc[1][0], 0,0,0);
      acc[0][1] = __builtin_amdgcn_mfma_f32_16x16x32_bf16(a0, b1, acc[0][1], 0,0,0);
      acc[1][1] = __builtin_amdgcn_mfma_f32_16x16x32_bf16(a1, b1, acc[1][1], 0,0,0);
    }
    if (it + 1 < NITER){
      const int nb = buf ^ 1;
      const int set = (it + 1) & 1;
      #pragma unroll
      for (int i = 0; i < 2; i++) *(bf16x8*)&As[nb][arow[i]][ac8[i]*8] = Ar[set][i];
      #pragma unroll
      for (int i = 0; i < 2; i++) *(bf16x8*)&Bs[nb][arow[i]][ac8[i]*8] = Br[set][i];
      if (it + 2 < NITER){
        const int s2 = it & 1;
        const size_t k2 = (size_t)(it + 2) * 64;
        #pragma unroll
        for (int i = 0; i < 2; i++) Ar[s2][i] = *(const bf16x8*)(A + aoff[i] + k2);
        #pragma unroll
        for (int i = 0; i < 2; i++) Br[s2][i] = *(const bf16x8*)(Bt + boff[i] + k2);
      }
      __syncthreads();
    }
  }

  #pragma unroll
  for (int i = 0; i < 2; i++){
    #pragma unroll
    for (int j = 0; j < 2; j++){
      int c = col0 + wn*32 + j*16 + l15;
      float bs = bias[c];
      #pragma unroll
      for (int r = 0; r < 4; r++){
        int rr = row0 + wm*32 + i*16 + q*4 + r;
        float v = tanh_f(acc[i][j][r] + bs);
        Y[(size_t)rr*NPAD + c] = __float2bfloat16(v);
      }
    }
  }
}

// ---------------------------------------------------------------------------
// GEMV: Ei[m] = H[m,:240] . w3 + b3 ; one wave per row. H is bf16 [m][256].
// ---------------------------------------------------------------------------
__global__ __launch_bounds__(256) void gemv_out(
    const __hip_bfloat16* __restrict__ H, const float* __restrict__ w3,
    const float* __restrict__ b3, float* __restrict__ Ei,
    float* __restrict__ outEi)
{
  int row  = (blockIdx.x * 256 + threadIdx.x) >> 6;
  int lane = threadIdx.x & 63;
  const __hip_bfloat16* hp = H + (size_t)row * NPAD;
  float a = 0.f;
  for (int k = lane; k < F0; k += 64) a = fmaf(__bfloat162float(hp[k]), w3[k], a);
  #pragma unroll
  for (int off = 32; off; off >>= 1) a += __shfl_down(a, off, 64);
  if (lane == 0){
    float e = a + b3[0];
    Ei[row] = e;
    outEi[row] = e;
  }
}

__global__ __launch_bounds__(256) void etot_k(
    const float* __restrict__ Ei, float* __restrict__ outE)
{
  int b = blockIdx.x;
  int t = threadIdx.x;
  float s = Ei[b*N_ + t] + Ei[b*N_ + 256 + t];
  #pragma unroll
  for (int off = 32; off; off >>= 1) s += __shfl_down(s, off, 64);
  __shared__ float ws[4];
  if ((t & 63) == 0) ws[t >> 6] = s;
  __syncthreads();
  if (t == 0) outE[b] = ws[0] + ws[1] + ws[2] + ws[3];
}

extern "C" void kernel_launch(void* const* d_in, const int* in_sizes, int n_in,
                              void* d_out, int out_size, void* d_ws, size_t ws_size,
                              hipStream_t stream)
{
  const float* img = (const float*)d_in[0];
  const float* ew0 = (const float*)d_in[1];
  const float* eb0 = (const float*)d_in[2];
  const float* ew1 = (const float*)d_in[3];
  const float* eb1 = (const float*)d_in[4];
  const float* ew2 = (const float*)d_in[5];
  const float* eb2 = (const float*)d_in[6];
  const float* fw0 = (const float*)d_in[7];
  const float* fb0 = (const float*)d_in[8];
  const float* fw1 = (const float*)d_in[9];
  const float* fb1 = (const float*)d_in[10];
  const float* fw2 = (const float*)d_in[11];
  const float* fb2 = (const float*)d_in[12];
  const float* fw3 = (const float*)d_in[13];
  const float* fb3 = (const float*)d_in[14];

  char* w = (char*)d_ws;
  __hip_bfloat16* DRb = (__hip_bfloat16*)(w);                 // 13107200 B
  __hip_bfloat16* H1b = (__hip_bfloat16*)(w + 13107200);      // 2097152 B
  __hip_bfloat16* H2b = (__hip_bfloat16*)(w + 15204352);
  __hip_bfloat16* H3b = (__hip_bfloat16*)(w + 17301504);
  __hip_bfloat16* W0T = (__hip_bfloat16*)(w + 19398656);      // 819200 B
  __hip_bfloat16* W1T = (__hip_bfloat16*)(w + 20217856);      // 131072 B
  __hip_bfloat16* W2T = (__hip_bfloat16*)(w + 20348928);      // 131072 B
  float* b0p = (float*)(w + 20480000);                        // 1024 B
  float* b1p = (float*)(w + 20481024);
  float* b2p = (float*)(w + 20482048);
  float2* LUT2 = (float2*)(w + 20483072);                     // 2097152 B
  float* Ei  = (float*)(w + 22580224);                        // 16384 B

  float* out = (float*)d_out;                                 // [0..7]=Etot, [8..]=Ei

  prep_fused<<<W0T_BLOCKS + SMALL_BLOCKS + LUT_BLOCKS, 256, 0, stream>>>(
      fw0, fw1, fw2, fb0, fb1, fb2,
      ew0, eb0, ew1, eb1, ew2, eb2,
      W0T, W1T, W2T, b0p, b1p, b2p, LUT2);

  embed_kernel<<<NPAIR, 128, 0, stream>>>(img, LUT2, DRb);

  dim3 gg(NPAIR/64, NPAD/64);
  gemm_lds<DRLEN, 25><<<gg, 256, 0, stream>>>(DRb, W0T, b0p, H1b);
  gemm_lds<NPAD,   4><<<gg, 256, 0, stream>>>(H1b, W1T, b1p, H2b);
  gemm_lds<NPAD,   4><<<gg, 256, 0, stream>>>(H2b, W2T, b2p, H3b);

  gemv_out<<<NPAIR/4, 256, 0, stream>>>(H3b, fw3, fb3, Ei, out + 8);
  etot_k<<<B_, 256, 0, stream>>>(Ei, out);
}

// Round 10
// 150.321 us; speedup vs baseline: 1.0123x; 1.0123x over previous
//
#include <hip/hip_runtime.h>
#include <hip/hip_bf16.h>
#include <math.h>

#define B_ 8
#define N_ 512
#define K_ 128
#define M_ 100
#define NPAIR (B_*N_)    // 4096
#define DRLEN 1600
#define F0 240
#define NPAD 256

#define NLUT 2048
#define LUT2_STRIDE 128      // float2 per row (100 used)
#define SMAX 1.5f
#define EPB 8                // LUT entries per block

using bf16x8 = __attribute__((ext_vector_type(8))) __bf16;
using f32x4  = __attribute__((ext_vector_type(4))) float;

static __device__ __forceinline__ float tanh_f(float x){
  float xc = fminf(fmaxf(x, -15.f), 15.f);
  float e = __expf(2.f*xc);
  return __fdividef(e - 1.f, e + 1.f);
}

// ---------------------------------------------------------------------------
// Fused prep: region A = W0 transpose, region B = W1T/W2T/bias, region C =
// LUT build (paired layout: T2[e][m] = (G_e[m], G_{e+1}[m])).
// ---------------------------------------------------------------------------
#define W0T_BLOCKS 100                                 // 25 x 4 tiles
#define SMALL_ELEMS (2*NPAD*NPAD + 3*NPAD)             // 131840
#define SMALL_BLOCKS ((SMALL_ELEMS + 255)/256)         // 515
#define LUT_BLOCKS (NLUT/EPB)                          // 256

__global__ __launch_bounds__(256) void prep_fused(
    const float* __restrict__ fw0, const float* __restrict__ fw1,
    const float* __restrict__ fw2,
    const float* __restrict__ fb0, const float* __restrict__ fb1,
    const float* __restrict__ fb2,
    const float* __restrict__ ew0, const float* __restrict__ eb0,
    const float* __restrict__ ew1, const float* __restrict__ eb1,
    const float* __restrict__ ew2, const float* __restrict__ eb2,
    __hip_bfloat16* __restrict__ W0T, __hip_bfloat16* __restrict__ W1T,
    __hip_bfloat16* __restrict__ W2T,
    float* __restrict__ b0p, float* __restrict__ b1p, float* __restrict__ b2p,
    float2* __restrict__ T2)
{
  __shared__ float tile[64][65];
  __shared__ float sh0[EPB][26];
  __shared__ float sh1[EPB][52];
  const int bb = blockIdx.x;
  const int t = threadIdx.x;

  if (bb < W0T_BLOCKS){
    const int k0 = (bb % 25) * 64;
    const int n0 = (bb / 25) * 64;
    const int tc = t & 63, tr = t >> 6;
    #pragma unroll
    for (int i = 0; i < 16; i++){
      int r = i*4 + tr;
      int n = n0 + tc;
      tile[r][tc] = (n < F0) ? fw0[(size_t)(k0 + r)*F0 + n] : 0.f;
    }
    __syncthreads();
    #pragma unroll
    for (int i = 0; i < 16; i++){
      int r = i*4 + tr;
      W0T[(size_t)(n0 + r)*DRLEN + k0 + tc] = __float2bfloat16(tile[tc][r]);
    }
  } else if (bb < W0T_BLOCKS + SMALL_BLOCKS){
    int idx = (bb - W0T_BLOCKS)*256 + t;
    if (idx < NPAD*NPAD){
      int n = idx / NPAD, k = idx % NPAD;
      W1T[idx] = __float2bfloat16((n < F0 && k < F0) ? fw1[(size_t)k*F0 + n] : 0.f);
    } else if (idx < 2*NPAD*NPAD){
      int j = idx - NPAD*NPAD;
      int n = j / NPAD, k = j % NPAD;
      W2T[j] = __float2bfloat16((n < F0 && k < F0) ? fw2[(size_t)k*F0 + n] : 0.f);
    } else if (idx < SMALL_ELEMS){
      int j = idx - 2*NPAD*NPAD;
      int which = j / NPAD, c = j % NPAD;
      const float* s = (which == 0) ? fb0 : (which == 1) ? fb1 : fb2;
      float* d = (which == 0) ? b0p : (which == 1) ? b1p : b2p;
      d[c] = (c < F0) ? s[c] : 0.f;
    }
  } else {
    const int e0 = (bb - W0T_BLOCKS - SMALL_BLOCKS) * EPB;
    if (t < EPB*25){
      int e = t / 25, c = t % 25;
      float S = (float)(e0 + e) * (SMAX / (float)(NLUT - 1));
      sh0[e][c] = tanh_f(fmaf(S, ew0[c], eb0[c]));
    }
    __syncthreads();
    for (int o = t; o < EPB*50; o += 256){
      int e = o / 50, c = o % 50;
      float a = eb1[c], b = 0.f;
      #pragma unroll
      for (int k = 0; k < 24; k += 2){
        a = fmaf(sh0[e][k],   ew1[k*50 + c],     a);
        b = fmaf(sh0[e][k+1], ew1[(k+1)*50 + c], b);
      }
      a = fmaf(sh0[e][24], ew1[24*50 + c], a);
      sh1[e][c] = tanh_f(a + b);
    }
    __syncthreads();
    for (int o = t; o < EPB*M_; o += 256){
      int e = o / M_, c = o % M_;
      float a = eb2[c], b = 0.f;
      #pragma unroll
      for (int k = 0; k < 50; k += 2){
        a = fmaf(sh1[e][k],   ew2[k*M_ + c],     a);
        b = fmaf(sh1[e][k+1], ew2[(k+1)*M_ + c], b);
      }
      float g = tanh_f(a + b);
      int ge = e0 + e;
      T2[(size_t)ge*LUT2_STRIDE + c].x = g;
      if (ge > 0)
        T2[(size_t)(ge-1)*LUT2_STRIDE + c].y = g;
    }
  }
}

// ---------------------------------------------------------------------------
// Embed: per (b,n) pair. ALL 128 j processed (inactive j with R>=10 still
// contribute S via the cos-taper branch -- no prefix skip, see r9 bug).
// 8-way unroll, split accumulators: 8 independent loads + chains in flight.
// ---------------------------------------------------------------------------
__global__ __launch_bounds__(128) void embed_kernel(
    const float* __restrict__ img, const float2* __restrict__ T2,
    __hip_bfloat16* __restrict__ DR)
{
  __shared__ float4 sRi[K_];
  __shared__ int    sJ[K_];      // premultiplied row offset (i * LUT2_STRIDE)
  __shared__ float  sW[K_];
  __shared__ float  sB[4][M_];

  const int pair = blockIdx.x;
  const int t = threadIdx.x;

  {
    float4 v = *(const float4*)(img + ((size_t)pair*K_ + t)*4);
    float x = v.x, y = v.y, z = v.z, fl = v.w;
    float R = fmaf(x, x, fmaf(y, y, z*z));
    bool mask = fl > 0.f;
    bool lt10 = R < 10.f;
    float safe = (R == 0.f) ? 1.f : R;
    float Sc = 0.5f*cosf(0.20943951023931953f*(R - 10.f)) + 0.5f;
    float S;
    if (mask && lt10)            S = 1.f/safe;
    else if (!lt10 && R < 25.f)  S = Sc;
    else                         S = 0.f;
    float coef = mask ? S/safe : 0.f;
    sRi[t] = make_float4(S, coef*x, coef*y, coef*z);

    float fidx = fminf(S, SMAX) * ((float)(NLUT - 1) / SMAX);
    float fi = floorf(fidx);
    int i = (int)fi;
    float w = fidx - fi;
    if (i > NLUT - 2){ i = NLUT - 2; w = 1.f; }
    sJ[t] = i * LUT2_STRIDE;
    sW[t] = w;
  }
  __syncthreads();

  if (t < M_){
    const int m = t;
    float a0[4] = {0.f,0.f,0.f,0.f};
    float a1[4] = {0.f,0.f,0.f,0.f};
    for (int j = 0; j < K_; j += 8){
      float2 tv[8];
      #pragma unroll
      for (int u = 0; u < 8; u++) tv[u] = T2[sJ[j+u] + m];
      #pragma unroll
      for (int u = 0; u < 8; u++){
        float g = fmaf(sW[j+u], tv[u].y - tv[u].x, tv[u].x);
        float4 ri = sRi[j+u];
        if ((u & 1) == 0){
          a0[0] = fmaf(ri.x, g, a0[0]);
          a0[1] = fmaf(ri.y, g, a0[1]);
          a0[2] = fmaf(ri.z, g, a0[2]);
          a0[3] = fmaf(ri.w, g, a0[3]);
        } else {
          a1[0] = fmaf(ri.x, g, a1[0]);
          a1[1] = fmaf(ri.y, g, a1[1]);
          a1[2] = fmaf(ri.z, g, a1[2]);
          a1[3] = fmaf(ri.w, g, a1[3]);
        }
      }
    }
    sB[0][m] = a0[0] + a1[0];
    sB[1][m] = a0[1] + a1[1];
    sB[2][m] = a0[2] + a1[2];
    sB[3][m] = a0[3] + a1[3];
  }
  __syncthreads();

  __hip_bfloat16* drp = DR + (size_t)pair*DRLEN;
  for (int o = t; o < DRLEN; o += 128){
    int m = o / M_, h = o % M_;
    float d = sB[0][m]*sB[0][h] + sB[1][m]*sB[1][h]
            + sB[2][m]*sB[2][h] + sB[3][m]*sB[3][h];
    drp[o] = __float2bfloat16(d);
  }
}

// ---------------------------------------------------------------------------
// LDS double-buffered MFMA GEMM, fully unrolled (compile-time indices).
// Y[M][256] = tanh(A @ Bt^T + bias). BM=BN=BK=64, 4 waves 2x2, tile 32x32.
// ---------------------------------------------------------------------------
template<int KK, int NITER>
__global__ __launch_bounds__(256) void gemm_lds(
    const __hip_bfloat16* __restrict__ A_, const __hip_bfloat16* __restrict__ Bt_,
    const float* __restrict__ bias, __hip_bfloat16* __restrict__ Y)
{
  __shared__ __align__(16) __bf16 As[2][64][72];
  __shared__ __align__(16) __bf16 Bs[2][64][72];

  const __bf16* A  = (const __bf16*)A_;
  const __bf16* Bt = (const __bf16*)Bt_;
  const int tid = threadIdx.x;
  const int lane = tid & 63, wave = tid >> 6;
  const int wm = wave & 1, wn = wave >> 1;
  const int l15 = lane & 15, q = lane >> 4;
  const int row0 = blockIdx.x * 64;
  const int col0 = blockIdx.y * 64;

  int arow[2], ac8[2]; size_t aoff[2], boff[2];
  #pragma unroll
  for (int i = 0; i < 2; i++){
    int cid = tid + i*256; arow[i] = cid >> 3; ac8[i] = cid & 7;
    aoff[i] = (size_t)(row0 + arow[i])*KK + ac8[i]*8;
    boff[i] = (size_t)(col0 + arow[i])*KK + ac8[i]*8;
  }

  bf16x8 Ar[2][2], Br[2][2];

  #pragma unroll
  for (int i = 0; i < 2; i++) Ar[0][i] = *(const bf16x8*)(A + aoff[i]);
  #pragma unroll
  for (int i = 0; i < 2; i++) Br[0][i] = *(const bf16x8*)(Bt + boff[i]);
  #pragma unroll
  for (int i = 0; i < 2; i++) *(bf16x8*)&As[0][arow[i]][ac8[i]*8] = Ar[0][i];
  #pragma unroll
  for (int i = 0; i < 2; i++) *(bf16x8*)&Bs[0][arow[i]][ac8[i]*8] = Br[0][i];
  #pragma unroll
  for (int i = 0; i < 2; i++) Ar[1][i] = *(const bf16x8*)(A + aoff[i] + 64);
  #pragma unroll
  for (int i = 0; i < 2; i++) Br[1][i] = *(const bf16x8*)(Bt + boff[i] + 64);
  __syncthreads();

  f32x4 acc[2][2] = {};

  #pragma unroll
  for (int it = 0; it < NITER; it++){
    const int buf = it & 1;
    #pragma unroll
    for (int ks = 0; ks < 2; ks++){
      bf16x8 a0 = *(const bf16x8*)&As[buf][wm*32 +      l15][ks*32 + q*8];
      bf16x8 a1 = *(const bf16x8*)&As[buf][wm*32 + 16 + l15][ks*32 + q*8];
      bf16x8 b0 = *(const bf16x8*)&Bs[buf][wn*32 +      l15][ks*32 + q*8];
      bf16x8 b1 = *(const bf16x8*)&Bs[buf][wn*32 + 16 + l15][ks*32 + q*8];
      acc[0][0] = __builtin_amdgcn_mfma_f32_16x16x32_bf16(a0, b0, acc[0][0], 0,0,0);
      acc[1][0] = __builtin_amdgcn_mfma_f32_16x16x32_bf16(a1, b0, acc[1][0], 0,0,0);
      acc[0][1] = __builtin_amdgcn_mfma_f32_16x16x32_bf16(a0, b1, acc[0][1], 0,0,0);
      acc[1][1] = __builtin_amdgcn_mfma_f32_16x16x32_bf16(a1, b1, acc[1][1], 0,0,0);
    }
    if (it + 1 < NITER){
      const int nb = buf ^ 1;
      const int set = (it + 1) & 1;
      #pragma unroll
      for (int i = 0; i < 2; i++) *(bf16x8*)&As[nb][arow[i]][ac8[i]*8] = Ar[set][i];
      #pragma unroll
      for (int i = 0; i < 2; i++) *(bf16x8*)&Bs[nb][arow[i]][ac8[i]*8] = Br[set][i];
      if (it + 2 < NITER){
        const int s2 = it & 1;
        const size_t k2 = (size_t)(it + 2) * 64;
        #pragma unroll
        for (int i = 0; i < 2; i++) Ar[s2][i] = *(const bf16x8*)(A + aoff[i] + k2);
        #pragma unroll
        for (int i = 0; i < 2; i++) Br[s2][i] = *(const bf16x8*)(Bt + boff[i] + k2);
      }
      __syncthreads();
    }
  }

  #pragma unroll
  for (int i = 0; i < 2; i++){
    #pragma unroll
    for (int j = 0; j < 2; j++){
      int c = col0 + wn*32 + j*16 + l15;
      float bs = bias[c];
      #pragma unroll
      for (int r = 0; r < 4; r++){
        int rr = row0 + wm*32 + i*16 + q*4 + r;
        float v = tanh_f(acc[i][j][r] + bs);
        Y[(size_t)rr*NPAD + c] = __float2bfloat16(v);
      }
    }
  }
}

// ---------------------------------------------------------------------------
// GEMV: Ei[m] = H[m,:240] . w3 + b3 ; one wave per row. H is bf16 [m][256].
// ---------------------------------------------------------------------------
__global__ __launch_bounds__(256) void gemv_out(
    const __hip_bfloat16* __restrict__ H, const float* __restrict__ w3,
    const float* __restrict__ b3, float* __restrict__ Ei,
    float* __restrict__ outEi)
{
  int row  = (blockIdx.x * 256 + threadIdx.x) >> 6;
  int lane = threadIdx.x & 63;
  const __hip_bfloat16* hp = H + (size_t)row * NPAD;
  float a = 0.f;
  for (int k = lane; k < F0; k += 64) a = fmaf(__bfloat162float(hp[k]), w3[k], a);
  #pragma unroll
  for (int off = 32; off; off >>= 1) a += __shfl_down(a, off, 64);
  if (lane == 0){
    float e = a + b3[0];
    Ei[row] = e;
    outEi[row] = e;
  }
}

__global__ __launch_bounds__(256) void etot_k(
    const float* __restrict__ Ei, float* __restrict__ outE)
{
  int b = blockIdx.x;
  int t = threadIdx.x;
  float s = Ei[b*N_ + t] + Ei[b*N_ + 256 + t];
  #pragma unroll
  for (int off = 32; off; off >>= 1) s += __shfl_down(s, off, 64);
  __shared__ float ws[4];
  if ((t & 63) == 0) ws[t >> 6] = s;
  __syncthreads();
  if (t == 0) outE[b] = ws[0] + ws[1] + ws[2] + ws[3];
}

extern "C" void kernel_launch(void* const* d_in, const int* in_sizes, int n_in,
                              void* d_out, int out_size, void* d_ws, size_t ws_size,
                              hipStream_t stream)
{
  const float* img = (const float*)d_in[0];
  const float* ew0 = (const float*)d_in[1];
  const float* eb0 = (const float*)d_in[2];
  const float* ew1 = (const float*)d_in[3];
  const float* eb1 = (const float*)d_in[4];
  const float* ew2 = (const float*)d_in[5];
  const float* eb2 = (const float*)d_in[6];
  const float* fw0 = (const float*)d_in[7];
  const float* fb0 = (const float*)d_in[8];
  const float* fw1 = (const float*)d_in[9];
  const float* fb1 = (const float*)d_in[10];
  const float* fw2 = (const float*)d_in[11];
  const float* fb2 = (const float*)d_in[12];
  const float* fw3 = (const float*)d_in[13];
  const float* fb3 = (const float*)d_in[14];

  char* w = (char*)d_ws;
  __hip_bfloat16* DRb = (__hip_bfloat16*)(w);                 // 13107200 B
  __hip_bfloat16* H1b = (__hip_bfloat16*)(w + 13107200);      // 2097152 B
  __hip_bfloat16* H2b = (__hip_bfloat16*)(w + 15204352);
  __hip_bfloat16* H3b = (__hip_bfloat16*)(w + 17301504);
  __hip_bfloat16* W0T = (__hip_bfloat16*)(w + 19398656);      // 819200 B
  __hip_bfloat16* W1T = (__hip_bfloat16*)(w + 20217856);      // 131072 B
  __hip_bfloat16* W2T = (__hip_bfloat16*)(w + 20348928);      // 131072 B
  float* b0p = (float*)(w + 20480000);                        // 1024 B
  float* b1p = (float*)(w + 20481024);
  float* b2p = (float*)(w + 20482048);
  float2* LUT2 = (float2*)(w + 20483072);                     // 2097152 B
  float* Ei  = (float*)(w + 22580224);                        // 16384 B

  float* out = (float*)d_out;                                 // [0..7]=Etot, [8..]=Ei

  prep_fused<<<W0T_BLOCKS + SMALL_BLOCKS + LUT_BLOCKS, 256, 0, stream>>>(
      fw0, fw1, fw2, fb0, fb1, fb2,
      ew0, eb0, ew1, eb1, ew2, eb2,
      W0T, W1T, W2T, b0p, b1p, b2p, LUT2);

  embed_kernel<<<NPAIR, 128, 0, stream>>>(img, LUT2, DRb);

  dim3 gg(NPAIR/64, NPAD/64);
  gemm_lds<DRLEN, 25><<<gg, 256, 0, stream>>>(DRb, W0T, b0p, H1b);
  gemm_lds<NPAD,   4><<<gg, 256, 0, stream>>>(H1b, W1T, b1p, H2b);
  gemm_lds<NPAD,   4><<<gg, 256, 0, stream>>>(H2b, W2T, b2p, H3b);

  gemv_out<<<NPAIR/4, 256, 0, stream>>>(H3b, fw3, fb3, Ei, out + 8);
  etot_k<<<B_, 256, 0, stream>>>(Ei, out);
}